// Round 1
// baseline (5365.986 us; speedup 1.0000x reference)
//
#include <hip/hip_runtime.h>

#define N_NODES 25000
#define N_EDGES 400000
#define S 64
#define V 32
#define L2C 16
#define TDIM 64
#define D 336          // S + 6V + 5*L2
#define FILMD 208

__device__ __forceinline__ float silu_f(float x) { return x / (1.0f + __expf(-x)); }

__device__ __forceinline__ float wsum64(float x) {
    #pragma unroll
    for (int m = 32; m > 0; m >>= 1) x += __shfl_xor(x, m, 64);
    return x;
}
__device__ __forceinline__ float wsum32(float x) {
    #pragma unroll
    for (int m = 16; m > 0; m >>= 1) x += __shfl_xor(x, m, 32);
    return x;
}
__device__ __forceinline__ float wsum16(float x) {
    #pragma unroll
    for (int m = 8; m > 0; m >>= 1) x += __shfl_xor(x, m, 16);
    return x;
}

// One wave (64 lanes) per edge. 4 waves per 256-thread block.
// Per-wave LDS scratch layout (floats):
//   es[252] | hid[128] | w[432] | dv[32] | ql[16] | sv[32] | eci[48] | t112[160] | sl[16]  -> 1116
__global__ __launch_bounds__(256) void edge_kernel(
    const float* __restrict__ h, const float* __restrict__ coords,
    const int* __restrict__ eidx,
    const int* __restrict__ etype, const int* __restrict__ ebt,
    const int* __restrict__ econj, const int* __restrict__ ering,
    const int* __restrict__ est, const float* __restrict__ eref,
    const float* __restrict__ t_emb,
    const float* __restrict__ type_emb, const float* __restrict__ bt_emb,
    const float* __restrict__ conj_emb, const float* __restrict__ ring_emb,
    const float* __restrict__ st_emb,
    const float* __restrict__ refW, const float* __restrict__ refb,
    const float* __restrict__ W1, const float* __restrict__ b1,
    const float* __restrict__ W2, const float* __restrict__ b2,
    const float* __restrict__ Wvs, const float* __restrict__ Wls,
    const float* __restrict__ Wsv, const float* __restrict__ Wlv,
    const float* __restrict__ Wvl, const float* __restrict__ Wsl,
    float* __restrict__ agg)
{
    __shared__ float lds[4][1120];
    const int wid = threadIdx.x >> 6;
    const int l   = threadIdx.x & 63;
    const int e   = blockIdx.x * 4 + wid;
    if (e >= N_EDGES) return;

    float* es   = lds[wid];
    float* hid  = es + 252;
    float* wbuf = hid + 128;
    float* dv   = wbuf + 432;
    float* ql   = dv + 32;
    float* sv   = ql + 16;
    float* eci  = sv + 32;
    float* t112 = eci + 48;
    float* sl   = t112 + 160;

    const int src = eidx[e];
    const int dst = eidx[N_EDGES + e];

    // ---- geometry (all lanes redundantly) ----
    const float* cs = coords + 3 * src;
    const float* cd = coords + 3 * dst;
    const float dx = cd[0] - cs[0], dy = cd[1] - cs[1], dz = cd[2] - cs[2];
    const float dist = sqrtf(dx * dx + dy * dy + dz * dz + 1e-12f);
    const float inv = 1.0f / dist;
    const float ux = dx * inv, uy = dy * inv, uz = dz * inv;
    const float R2 = 0.7071067811865476f;
    const float R6 = 0.4082482904638631f;
    float y2a[5];
    y2a[0] = 2.f * R2 * ux * uy;
    y2a[1] = 2.f * R2 * ux * uz;
    y2a[2] = 2.f * R2 * uy * uz;
    y2a[3] = R2 * (ux * ux - uy * uy);
    y2a[4] = R6 * (ux * ux + uy * uy - 2.f * uz * uz);

    // ---- build es[252] in LDS ----
    es[60 + l]  = h[(size_t)src * D + l];
    es[124 + l] = h[(size_t)dst * D + l];
    es[188 + l] = t_emb[(size_t)dst * TDIM + l];
    {
        const int et = etype[e];
        const int bt = ebt[e];
        const int ci = (bt >= 0) ? econj[e] : 2;
        const int ri = (bt >= 0) ? ering[e] : 2;
        const int si = est[e] + 1;
        const float er = eref[e];
        if (l < 16) {
            const float mu = (float)l * (5.0f / 15.0f);
            const float t = (dist - mu) * 3.0f;
            es[l] = __expf(-t * t);
            es[16 + l] = type_emb[et * 16 + l];
        }
        if (l < 8) {
            es[32 + l] = bt_emb[(bt + 1) * 8 + l];
            const float ddv = dist - er;
            const float hr = (er > 0.f) ? 1.f : 0.f;
            es[52 + l] = fabsf(ddv) * refW[l] + ddv * refW[8 + l] + hr * refW[16 + l] + refb[l];
        }
        if (l < 4) {
            es[40 + l] = conj_emb[ci * 4 + l];
            es[44 + l] = ring_emb[ri * 4 + l];
            es[48 + l] = st_emb[si * 4 + l];
        }
    }

    // ---- MLP layer 1: hid = silu(es @ W1 + b1), lane handles cols l, l+64 ----
    {
        float a0 = b1[l], a1 = b1[64 + l];
        #pragma unroll 4
        for (int k = 0; k < 252; k++) {
            const float ek = es[k];
            const float* Wk = W1 + k * 128;
            a0 = fmaf(ek, Wk[l], a0);
            a1 = fmaf(ek, Wk[64 + l], a1);
        }
        hid[l] = silu_f(a0);
        hid[64 + l] = silu_f(a1);
    }

    // ---- MLP layer 2: w = hid @ W2 + b2, lane handles cols l+64r, r=0..6 ----
    {
        const bool v6 = (384 + l) < 432;
        const int c6 = v6 ? (384 + l) : 0;
        float a0 = b2[l], a1 = b2[64 + l], a2 = b2[128 + l];
        float a3 = b2[192 + l], a4 = b2[256 + l], a5 = b2[320 + l];
        float a6 = v6 ? b2[c6] : 0.f;
        #pragma unroll 2
        for (int k = 0; k < 128; k++) {
            const float hk = hid[k];
            const float* Wk = W2 + k * 432;
            a0 = fmaf(hk, Wk[l], a0);
            a1 = fmaf(hk, Wk[64 + l], a1);
            a2 = fmaf(hk, Wk[128 + l], a2);
            a3 = fmaf(hk, Wk[192 + l], a3);
            a4 = fmaf(hk, Wk[256 + l], a4);
            a5 = fmaf(hk, Wk[320 + l], a5);
            a6 = fmaf(hk, Wk[c6], a6);
        }
        wbuf[l] = a0; wbuf[64 + l] = a1; wbuf[128 + l] = a2;
        wbuf[192 + l] = a3; wbuf[256 + l] = a4; wbuf[320 + l] = a5;
        if (v6) wbuf[384 + l] = a6;
    }

    // ---- helper arrays ----
    float h1o0 = 0, h1o1 = 0, h1o2 = 0, h1e0 = 0, h1e1 = 0, h1e2 = 0;
    float h2s0 = 0, h2s1 = 0, h2s2 = 0, h2s3 = 0, h2s4 = 0;
    if (l < 32) {
        const float* p = h + (size_t)src * D + S + 3 * l;
        h1o0 = p[0]; h1o1 = p[1]; h1o2 = p[2];
        const float* q = h + (size_t)src * D + S + 96 + 3 * l;
        h1e0 = q[0]; h1e1 = q[1]; h1e2 = q[2];
        dv[l] = h1o0 * ux + h1o1 * uy + h1o2 * uz;
        // t112[v][k] = h1o_v . By[k]
        t112[l * 5 + 0] = R2 * (h1o0 * uy + h1o1 * ux);
        t112[l * 5 + 1] = R2 * (h1o0 * uz + h1o2 * ux);
        t112[l * 5 + 2] = R2 * (h1o1 * uz + h1o2 * uy);
        t112[l * 5 + 3] = R2 * (h1o0 * ux - h1o1 * uy);
        t112[l * 5 + 4] = R6 * (h1o0 * ux + h1o1 * uy - 2.f * h1o2 * uz);
    } else {
        const int v = l - 32;
        float a = 0.f;
        #pragma unroll 4
        for (int j = 0; j < 64; j++) a = fmaf(es[60 + j], Wsv[j * 32 + v], a);
        sv[v] = a;
    }
    if (l < 16) {
        const float* p = h + (size_t)src * D + S + 192 + 5 * l;
        h2s0 = p[0]; h2s1 = p[1]; h2s2 = p[2]; h2s3 = p[3]; h2s4 = p[4];
        ql[l] = h2s0 * y2a[0] + h2s1 * y2a[1] + h2s2 * y2a[2] + h2s3 * y2a[3] + h2s4 * y2a[4];
        // eci[c][i] = sum_k h2s[c][k] * By[k][i]
        eci[l * 3 + 0] = R2 * (h2s0 * uy + h2s1 * uz + h2s3 * ux) + R6 * h2s4 * ux;
        eci[l * 3 + 1] = R2 * (h2s0 * ux + h2s2 * uz - h2s3 * uy) + R6 * h2s4 * uy;
        eci[l * 3 + 2] = R2 * (h2s1 * ux + h2s2 * uy) - 2.f * R6 * h2s4 * uz;
    } else if (l < 32) {
        const int c = l - 16;
        float a = 0.f;
        #pragma unroll 4
        for (int j = 0; j < 64; j++) a = fmaf(es[60 + j], Wsl[j * 16 + c], a);
        sl[c] = a;
    }

    float* arow = agg + (size_t)dst * D;

    // ---- m0 (all lanes, channel l) ----
    {
        const float w00 = wbuf[l], w10 = wbuf[64 + l], w20 = wbuf[128 + l];
        float t1 = 0.f, t2 = 0.f;
        #pragma unroll
        for (int v = 0; v < 32; v++) t1 = fmaf(dv[v], Wvs[v * 64 + l], t1);
        #pragma unroll
        for (int c = 0; c < 16; c++) t2 = fmaf(ql[c], Wls[c * 64 + l], t2);
        const float m0 = w00 * es[60 + l] + w10 * t1 + w20 * t2;
        atomicAdd(arow + l, m0);
    }

    // ---- m1o / m1e (lanes 0..31, v = l) ----
    if (l < 32) {
        const int v = l;
        const float w11o = wbuf[192 + v], w01o = wbuf[224 + v];
        const float wx1o = wbuf[256 + v], w21o = wbuf[288 + v];
        const float w11e = wbuf[320 + v], wx1e = wbuf[352 + v];
        const float co0 = h1e1 * uz - h1e2 * uy;
        const float co1 = h1e2 * ux - h1e0 * uz;
        const float co2 = h1e0 * uy - h1e1 * ux;
        const float ce0 = h1o1 * uz - h1o2 * uy;
        const float ce1 = h1o2 * ux - h1o0 * uz;
        const float ce2 = h1o0 * uy - h1o1 * ux;
        float t0 = 0.f, t1 = 0.f, t2 = 0.f;
        #pragma unroll
        for (int c = 0; c < 16; c++) {
            const float wl = Wlv[c * 32 + v];
            t0 = fmaf(eci[c * 3 + 0], wl, t0);
            t1 = fmaf(eci[c * 3 + 1], wl, t1);
            t2 = fmaf(eci[c * 3 + 2], wl, t2);
        }
        const float svv = sv[v];
        atomicAdd(arow + S + 3 * v + 0, w11o * h1o0 + w01o * svv * ux + wx1o * co0 + w21o * t0);
        atomicAdd(arow + S + 3 * v + 1, w11o * h1o1 + w01o * svv * uy + wx1o * co1 + w21o * t1);
        atomicAdd(arow + S + 3 * v + 2, w11o * h1o2 + w01o * svv * uz + wx1o * co2 + w21o * t2);
        atomicAdd(arow + 160 + 3 * v + 0, w11e * h1e0 + wx1e * ce0);
        atomicAdd(arow + 160 + 3 * v + 1, w11e * h1e1 + wx1e * ce1);
        atomicAdd(arow + 160 + 3 * v + 2, w11e * h1e2 + wx1e * ce2);
    }

    // ---- m2 (lanes 0..15, c = l) ----
    if (l < 16) {
        const int c = l;
        const float w22 = wbuf[384 + c], w112 = wbuf[400 + c], w02 = wbuf[416 + c];
        float tl0 = 0, tl1 = 0, tl2 = 0, tl3 = 0, tl4 = 0;
        #pragma unroll
        for (int v = 0; v < 32; v++) {
            const float wv = Wvl[v * 16 + c];
            tl0 = fmaf(t112[v * 5 + 0], wv, tl0);
            tl1 = fmaf(t112[v * 5 + 1], wv, tl1);
            tl2 = fmaf(t112[v * 5 + 2], wv, tl2);
            tl3 = fmaf(t112[v * 5 + 3], wv, tl3);
            tl4 = fmaf(t112[v * 5 + 4], wv, tl4);
        }
        const float slc = sl[c];
        atomicAdd(arow + 256 + 5 * c + 0, w22 * h2s0 + w112 * tl0 + w02 * slc * y2a[0]);
        atomicAdd(arow + 256 + 5 * c + 1, w22 * h2s1 + w112 * tl1 + w02 * slc * y2a[1]);
        atomicAdd(arow + 256 + 5 * c + 2, w22 * h2s2 + w112 * tl2 + w02 * slc * y2a[2]);
        atomicAdd(arow + 256 + 5 * c + 3, w22 * h2s3 + w112 * tl3 + w02 * slc * y2a[3]);
        atomicAdd(arow + 256 + 5 * c + 4, w22 * h2s4 + w112 * tl4 + w02 * slc * y2a[4]);
    }
}

// One wave per node: projections + FiLM + LayerNorm + equivariant RMS norms.
__global__ __launch_bounds__(256) void node_kernel(
    const float* __restrict__ h, const float* __restrict__ t_emb,
    const float* __restrict__ agg,
    const float* __restrict__ P0, const float* __restrict__ P1o,
    const float* __restrict__ P1e, const float* __restrict__ P2,
    const float* __restrict__ filmW, const float* __restrict__ filmb,
    float* __restrict__ out)
{
    __shared__ float lds[4][336 + 64];
    const int wid = threadIdx.x >> 6;
    const int l = threadIdx.x & 63;
    const int n = blockIdx.x * 4 + wid;
    if (n >= N_NODES) return;
    float* ag = lds[wid];
    float* tv = ag + 336;
    const float* arow = agg + (size_t)n * D;
    const float* hrow = h + (size_t)n * D;
    for (int i = l; i < 336; i += 64) ag[i] = arow[i];
    tv[l] = t_emb[(size_t)n * TDIM + l];

    // FiLM: lane l computes cols l, 64+l, 128+l, 192+(l&15)
    const int c2 = 128 + l;
    const int c3 = 192 + (l & 15);
    float f0 = filmb[l], f1 = filmb[64 + l], f2 = filmb[c2], f3 = filmb[c3];
    #pragma unroll 4
    for (int t = 0; t < 64; t++) {
        const float tt = tv[t];
        const float* fr = filmW + t * FILMD;
        f0 = fmaf(tt, fr[l], f0);
        f1 = fmaf(tt, fr[64 + l], f1);
        f2 = fmaf(tt, fr[c2], f2);
        f3 = fmaf(tt, fr[c3], f3);
    }

    // scalar channel + LayerNorm + FiLM
    {
        float a0 = 0.f;
        #pragma unroll 4
        for (int j = 0; j < 64; j++) a0 = fmaf(ag[j], P0[j * 64 + l], a0);
        a0 = silu_f(a0);
        const float hn0 = hrow[l] + a0;
        const float mu = wsum64(hn0) * (1.0f / 64.0f);
        const float d0 = hn0 - mu;
        const float var = wsum64(d0 * d0) * (1.0f / 64.0f);
        out[(size_t)n * D + l] = d0 * rsqrtf(var + 1e-6f) * (1.f + f0) + f1;
    }

    // vector channels: lanes 0..31 -> odd-parity (h1o,P1o), lanes 32..63 -> even (h1e,P1e)
    {
        const int v = l & 31;
        const bool iso = (l < 32);
        const float* Pm = iso ? P1o : P1e;
        const int base = iso ? 64 : 160;
        float a0 = 0.f, a1 = 0.f, a2 = 0.f;
        #pragma unroll 4
        for (int u = 0; u < 32; u++) {
            const float p = Pm[u * 32 + v];
            a0 = fmaf(ag[base + 3 * u + 0], p, a0);
            a1 = fmaf(ag[base + 3 * u + 1], p, a1);
            a2 = fmaf(ag[base + 3 * u + 2], p, a2);
        }
        const float x0 = hrow[base + 3 * v + 0] + a0;
        const float x1 = hrow[base + 3 * v + 1] + a1;
        const float x2 = hrow[base + 3 * v + 2] + a2;
        const float ssq = x0 * x0 + x1 * x1 + x2 * x2;
        const float s = wsum32(ssq);
        const float rinv = rsqrtf(s * (1.f / 32.f) + 1e-6f);
        const float sc = (1.f + f2) * rinv;
        out[(size_t)n * D + base + 3 * v + 0] = x0 * sc;
        out[(size_t)n * D + base + 3 * v + 1] = x1 * sc;
        out[(size_t)n * D + base + 3 * v + 2] = x2 * sc;
    }

    // l=2 channels: lanes 0..15 effective (16..63 compute duplicates, don't store)
    {
        const int c = l & 15;
        float xk[5];
        float ssq = 0.f;
        #pragma unroll
        for (int k = 0; k < 5; k++) {
            float a = 0.f;
            #pragma unroll
            for (int u = 0; u < 16; u++) a = fmaf(ag[256 + 5 * u + k], P2[u * 16 + c], a);
            const float x = hrow[256 + 5 * c + k] + a;
            xk[k] = x;
            ssq += x * x;
        }
        const float s = wsum16(ssq);
        const float rinv = rsqrtf(s * (1.f / 16.f) + 1e-6f);
        const float sc = (1.f + f3) * rinv;
        if (l < 16) {
            #pragma unroll
            for (int k = 0; k < 5; k++) out[(size_t)n * D + 256 + 5 * c + k] = xk[k] * sc;
        }
    }
}

extern "C" void kernel_launch(void* const* d_in, const int* in_sizes, int n_in,
                              void* d_out, int out_size, void* d_ws, size_t ws_size,
                              hipStream_t stream)
{
    const float* h        = (const float*)d_in[0];
    const float* coords   = (const float*)d_in[1];
    const int*   eidx     = (const int*)d_in[2];
    const int*   etype    = (const int*)d_in[3];
    const int*   ebt      = (const int*)d_in[4];
    const int*   econj    = (const int*)d_in[5];
    const int*   ering    = (const int*)d_in[6];
    const int*   est      = (const int*)d_in[7];
    const float* eref     = (const float*)d_in[8];
    const float* t_emb    = (const float*)d_in[9];
    const float* type_emb = (const float*)d_in[10];
    const float* bt_emb   = (const float*)d_in[11];
    const float* conj_emb = (const float*)d_in[12];
    const float* ring_emb = (const float*)d_in[13];
    const float* st_emb   = (const float*)d_in[14];
    const float* refW     = (const float*)d_in[15];
    const float* refb     = (const float*)d_in[16];
    const float* W1       = (const float*)d_in[17];
    const float* b1       = (const float*)d_in[18];
    const float* W2       = (const float*)d_in[19];
    const float* b2       = (const float*)d_in[20];
    const float* Wvs      = (const float*)d_in[21];
    const float* Wls      = (const float*)d_in[22];
    const float* Wsv      = (const float*)d_in[23];
    const float* Wlv      = (const float*)d_in[24];
    const float* Wvl      = (const float*)d_in[25];
    const float* Wsl      = (const float*)d_in[26];
    const float* P0       = (const float*)d_in[27];
    const float* P1o      = (const float*)d_in[28];
    const float* P1e      = (const float*)d_in[29];
    const float* P2       = (const float*)d_in[30];
    const float* filmW    = (const float*)d_in[31];
    const float* filmb    = (const float*)d_in[32];

    float* out = (float*)d_out;
    float* agg = (float*)d_ws;   // N_NODES * D floats = 33.6 MB

    hipMemsetAsync(agg, 0, (size_t)N_NODES * D * sizeof(float), stream);

    edge_kernel<<<N_EDGES / 4, 256, 0, stream>>>(
        h, coords, eidx, etype, ebt, econj, ering, est, eref, t_emb,
        type_emb, bt_emb, conj_emb, ring_emb, st_emb, refW, refb,
        W1, b1, W2, b2, Wvs, Wls, Wsv, Wlv, Wvl, Wsl, agg);

    node_kernel<<<(N_NODES + 3) / 4, 256, 0, stream>>>(
        h, t_emb, agg, P0, P1o, P1e, P2, filmW, filmb, out);
}

// Round 2
// 2738.313 us; speedup vs baseline: 1.9596x; 1.9596x over previous
//
#include <hip/hip_runtime.h>
#include <hip/hip_bf16.h>

#define N_NODES 25000
#define N_EDGES 400000
#define S 64
#define V 32
#define L2C 16
#define TDIM 64
#define D 336          // S + 6V + 5*L2
#define FILMD 208

#define ES_STR 264     // es row stride in bf16 (252 used, pad->264 for banks)
#define HID_STR 136    // hid row stride in bf16
#define W_STR 440      // w row stride in bf16 (432 used)

typedef short bf8 __attribute__((ext_vector_type(8)));
typedef float f4  __attribute__((ext_vector_type(4)));

__device__ __forceinline__ float silu_f(float x) { return x / (1.0f + __expf(-x)); }

__device__ __forceinline__ float wsum64(float x) {
    #pragma unroll
    for (int m = 32; m > 0; m >>= 1) x += __shfl_xor(x, m, 64);
    return x;
}
__device__ __forceinline__ float wsum32(float x) {
    #pragma unroll
    for (int m = 16; m > 0; m >>= 1) x += __shfl_xor(x, m, 32);
    return x;
}
__device__ __forceinline__ float wsum16(float x) {
    #pragma unroll
    for (int m = 8; m > 0; m >>= 1) x += __shfl_xor(x, m, 16);
    return x;
}

// One-time per launch: transpose + bf16-convert MLP weights into workspace.
// Wb1t[n][k] = W1[k][n], n<128, k<256 (zero-pad k>=252). Wb2t[n][k] = W2[k][n], n<432, k<128.
__global__ __launch_bounds__(256) void convert_weights(
    const float* __restrict__ W1, const float* __restrict__ W2,
    __hip_bfloat16* __restrict__ Wb1t, __hip_bfloat16* __restrict__ Wb2t)
{
    const int i = blockIdx.x * 256 + threadIdx.x;
    if (i < 128 * 256) {
        const int n = i >> 8, k = i & 255;
        const float v = (k < 252) ? W1[k * 128 + n] : 0.0f;
        Wb1t[i] = __float2bfloat16(v);
    }
    if (i < 432 * 128) {
        const int n = i >> 7, k = i & 127;
        Wb2t[i] = __float2bfloat16(W2[k * 432 + n]);
    }
}

// Block = 256 threads (4 waves) = 64 edges.
// Stage1: build es[64][252] bf16 in LDS (+geometry). Stage2: MFMA GEMM1 (es@W1->hid, silu).
// Stage3: MFMA GEMM2 (hid@W2->w, bf16 in LDS, reusing es region). Stage4: per-edge message
// assembly + atomics into agg (round-1 structure, w read from LDS).
__global__ __launch_bounds__(256) void edge_kernel(
    const float* __restrict__ h, const float* __restrict__ coords,
    const int* __restrict__ eidx,
    const int* __restrict__ etype, const int* __restrict__ ebt,
    const int* __restrict__ econj, const int* __restrict__ ering,
    const int* __restrict__ est, const float* __restrict__ eref,
    const float* __restrict__ t_emb,
    const float* __restrict__ type_emb, const float* __restrict__ bt_emb,
    const float* __restrict__ conj_emb, const float* __restrict__ ring_emb,
    const float* __restrict__ st_emb,
    const float* __restrict__ refW, const float* __restrict__ refb,
    const __hip_bfloat16* __restrict__ Wb1t, const float* __restrict__ b1,
    const __hip_bfloat16* __restrict__ Wb2t, const float* __restrict__ b2,
    const float* __restrict__ Wvs, const float* __restrict__ Wls,
    const float* __restrict__ Wsv, const float* __restrict__ Wlv,
    const float* __restrict__ Wvl, const float* __restrict__ Wsl,
    float* __restrict__ agg)
{
    // uniA: es region (stride ES_STR, 64*264=16896 elems) overlaid by w (stride W_STR, 64*440=28160)
    __shared__ __hip_bfloat16 uniA[64 * W_STR];   // 56320 B
    __shared__ __hip_bfloat16 hidA[64 * HID_STR]; // 17408 B
    __shared__ float geomA[64 * 4];               // 1024 B
    __shared__ float scratch[4][304];             // 4864 B   total 79616 B -> 2 blocks/CU

    const int wid = threadIdx.x >> 6;
    const int l   = threadIdx.x & 63;
    const int ebase = blockIdx.x * 64;

    const float R2 = 0.7071067811865476f;
    const float R6 = 0.4082482904638631f;

    // ---------------- Stage 1: edge features -> es (bf16) ----------------
    for (int i = 0; i < 16; i++) {
        const int le = wid * 16 + i;
        const int e  = ebase + le;
        const int src = eidx[e];
        const int dst = eidx[N_EDGES + e];
        const float* cs = coords + 3 * src;
        const float* cd = coords + 3 * dst;
        const float dx = cd[0] - cs[0], dy = cd[1] - cs[1], dz = cd[2] - cs[2];
        const float dist = sqrtf(dx * dx + dy * dy + dz * dz + 1e-12f);
        const float inv = 1.0f / dist;
        const float ux = dx * inv, uy = dy * inv, uz = dz * inv;
        if (l < 4) {
            float g = (l == 0) ? ux : (l == 1) ? uy : (l == 2) ? uz : dist;
            geomA[le * 4 + l] = g;
        }
        __hip_bfloat16* es = uniA + le * ES_STR;
        es[60 + l]  = __float2bfloat16(h[(size_t)src * D + l]);
        es[124 + l] = __float2bfloat16(h[(size_t)dst * D + l]);
        es[188 + l] = __float2bfloat16(t_emb[(size_t)dst * TDIM + l]);
        const int et = etype[e];
        const int bt = ebt[e];
        const int ci = (bt >= 0) ? econj[e] : 2;
        const int ri = (bt >= 0) ? ering[e] : 2;
        const int si = est[e] + 1;
        const float er = eref[e];
        if (l < 16) {
            const float mu = (float)l * (5.0f / 15.0f);
            const float t = (dist - mu) * 3.0f;
            es[l] = __float2bfloat16(__expf(-t * t));
            es[16 + l] = __float2bfloat16(type_emb[et * 16 + l]);
        }
        if (l < 8) {
            es[32 + l] = __float2bfloat16(bt_emb[(bt + 1) * 8 + l]);
            const float ddv = dist - er;
            const float hr = (er > 0.f) ? 1.f : 0.f;
            es[52 + l] = __float2bfloat16(
                fabsf(ddv) * refW[l] + ddv * refW[8 + l] + hr * refW[16 + l] + refb[l]);
        }
        if (l < 4) {
            es[40 + l] = __float2bfloat16(conj_emb[ci * 4 + l]);
            es[44 + l] = __float2bfloat16(ring_emb[ri * 4 + l]);
            es[48 + l] = __float2bfloat16(st_emb[si * 4 + l]);
            es[252 + l] = __float2bfloat16(0.0f);  // K padding
        }
    }
    __syncthreads();

    // ---------------- Stage 2: GEMM1  hid[64x128] = silu(es @ W1 + b1) ----------------
    {
        const int q = l >> 4;       // quad
        const int t16 = l & 15;
        f4 acc[4][2];
        #pragma unroll
        for (int mt = 0; mt < 4; mt++)
            #pragma unroll
            for (int nt = 0; nt < 2; nt++) acc[mt][nt] = (f4){0.f, 0.f, 0.f, 0.f};
        const int n0 = wid * 32 + t16;        // column for nt=0
        #pragma unroll
        for (int kk = 0; kk < 256; kk += 32) {
            const int k0 = kk + q * 8;
            bf8 a[4];
            #pragma unroll
            for (int mt = 0; mt < 4; mt++)
                a[mt] = *(const bf8*)(uniA + (mt * 16 + t16) * ES_STR + k0);
            bf8 b[2];
            b[0] = *(const bf8*)(Wb1t + (size_t)n0 * 256 + k0);
            b[1] = *(const bf8*)(Wb1t + (size_t)(n0 + 16) * 256 + k0);
            #pragma unroll
            for (int mt = 0; mt < 4; mt++) {
                acc[mt][0] = __builtin_amdgcn_mfma_f32_16x16x32_bf16(a[mt], b[0], acc[mt][0], 0, 0, 0);
                acc[mt][1] = __builtin_amdgcn_mfma_f32_16x16x32_bf16(a[mt], b[1], acc[mt][1], 0, 0, 0);
            }
        }
        const float bias0 = b1[n0], bias1 = b1[n0 + 16];
        #pragma unroll
        for (int mt = 0; mt < 4; mt++) {
            #pragma unroll
            for (int r = 0; r < 4; r++) {
                const int m = mt * 16 + q * 4 + r;
                hidA[m * HID_STR + n0]      = __float2bfloat16(silu_f(acc[mt][0][r] + bias0));
                hidA[m * HID_STR + n0 + 16] = __float2bfloat16(silu_f(acc[mt][1][r] + bias1));
            }
        }
    }
    __syncthreads();   // hid complete; es region may now be overwritten by w

    // ---------------- Stage 3: GEMM2  w[64x432] = hid @ W2 + b2 (bf16 -> LDS) ----------------
    {
        const int q = l >> 4;
        const int t16 = l & 15;
        bf8 a2[4][4];
        #pragma unroll
        for (int ks = 0; ks < 4; ks++) {
            const int k0 = ks * 32 + q * 8;
            #pragma unroll
            for (int mt = 0; mt < 4; mt++)
                a2[mt][ks] = *(const bf8*)(hidA + (mt * 16 + t16) * HID_STR + k0);
        }
        for (int t = wid; t < 27; t += 4) {
            const int n = t * 16 + t16;
            f4 acc[4];
            #pragma unroll
            for (int mt = 0; mt < 4; mt++) acc[mt] = (f4){0.f, 0.f, 0.f, 0.f};
            #pragma unroll
            for (int ks = 0; ks < 4; ks++) {
                const bf8 b = *(const bf8*)(Wb2t + (size_t)n * 128 + ks * 32 + q * 8);
                #pragma unroll
                for (int mt = 0; mt < 4; mt++)
                    acc[mt] = __builtin_amdgcn_mfma_f32_16x16x32_bf16(a2[mt][ks], b, acc[mt], 0, 0, 0);
            }
            const float bias = b2[n];
            #pragma unroll
            for (int mt = 0; mt < 4; mt++) {
                #pragma unroll
                for (int r = 0; r < 4; r++) {
                    const int m = mt * 16 + q * 4 + r;
                    uniA[m * W_STR + n] = __float2bfloat16(acc[mt][r] + bias);
                }
            }
        }
    }
    __syncthreads();

    // ---------------- Stage 4: message assembly + scatter ----------------
    float* dv   = scratch[wid];
    float* ql   = dv + 32;
    float* sv   = ql + 16;
    float* eci  = sv + 32;
    float* t112 = eci + 48;
    float* sl   = t112 + 160;

    for (int i = 0; i < 16; i++) {
        const int le = wid * 16 + i;
        const int e  = ebase + le;
        const int src = eidx[e];
        const int dst = eidx[N_EDGES + e];
        const float ux = geomA[le * 4 + 0];
        const float uy = geomA[le * 4 + 1];
        const float uz = geomA[le * 4 + 2];
        float y2a[5];
        y2a[0] = 2.f * R2 * ux * uy;
        y2a[1] = 2.f * R2 * ux * uz;
        y2a[2] = 2.f * R2 * uy * uz;
        y2a[3] = R2 * (ux * ux - uy * uy);
        y2a[4] = R6 * (ux * ux + uy * uy - 2.f * uz * uz);

        const __hip_bfloat16* wrow = uniA + le * W_STR;

        float h1o0 = 0, h1o1 = 0, h1o2 = 0, h1e0 = 0, h1e1 = 0, h1e2 = 0;
        float h2s0 = 0, h2s1 = 0, h2s2 = 0, h2s3 = 0, h2s4 = 0;
        if (l < 32) {
            const float* p = h + (size_t)src * D + S + 3 * l;
            h1o0 = p[0]; h1o1 = p[1]; h1o2 = p[2];
            const float* qp = h + (size_t)src * D + S + 96 + 3 * l;
            h1e0 = qp[0]; h1e1 = qp[1]; h1e2 = qp[2];
            dv[l] = h1o0 * ux + h1o1 * uy + h1o2 * uz;
            t112[l * 5 + 0] = R2 * (h1o0 * uy + h1o1 * ux);
            t112[l * 5 + 1] = R2 * (h1o0 * uz + h1o2 * ux);
            t112[l * 5 + 2] = R2 * (h1o1 * uz + h1o2 * uy);
            t112[l * 5 + 3] = R2 * (h1o0 * ux - h1o1 * uy);
            t112[l * 5 + 4] = R6 * (h1o0 * ux + h1o1 * uy - 2.f * h1o2 * uz);
        } else {
            const int v = l - 32;
            float a = 0.f;
            #pragma unroll 4
            for (int j = 0; j < 64; j++) a = fmaf(h[(size_t)src * D + j], Wsv[j * 32 + v], a);
            sv[v] = a;
        }
        if (l < 16) {
            const float* p = h + (size_t)src * D + S + 192 + 5 * l;
            h2s0 = p[0]; h2s1 = p[1]; h2s2 = p[2]; h2s3 = p[3]; h2s4 = p[4];
            ql[l] = h2s0 * y2a[0] + h2s1 * y2a[1] + h2s2 * y2a[2] + h2s3 * y2a[3] + h2s4 * y2a[4];
            eci[l * 3 + 0] = R2 * (h2s0 * uy + h2s1 * uz + h2s3 * ux) + R6 * h2s4 * ux;
            eci[l * 3 + 1] = R2 * (h2s0 * ux + h2s2 * uz - h2s3 * uy) + R6 * h2s4 * uy;
            eci[l * 3 + 2] = R2 * (h2s1 * ux + h2s2 * uy) - 2.f * R6 * h2s4 * uz;
        } else if (l < 32) {
            const int c = l - 16;
            float a = 0.f;
            #pragma unroll 4
            for (int j = 0; j < 64; j++) a = fmaf(h[(size_t)src * D + j], Wsl[j * 16 + c], a);
            sl[c] = a;
        }

        float* arow = agg + (size_t)dst * D;

        // m0
        {
            const float w00 = __bfloat162float(wrow[l]);
            const float w10 = __bfloat162float(wrow[64 + l]);
            const float w20 = __bfloat162float(wrow[128 + l]);
            float t1 = 0.f, t2 = 0.f;
            #pragma unroll
            for (int v = 0; v < 32; v++) t1 = fmaf(dv[v], Wvs[v * 64 + l], t1);
            #pragma unroll
            for (int c = 0; c < 16; c++) t2 = fmaf(ql[c], Wls[c * 64 + l], t2);
            const float m0 = w00 * h[(size_t)src * D + l] + w10 * t1 + w20 * t2;
            atomicAdd(arow + l, m0);
        }

        // m1o / m1e
        if (l < 32) {
            const int v = l;
            const float w11o = __bfloat162float(wrow[192 + v]);
            const float w01o = __bfloat162float(wrow[224 + v]);
            const float wx1o = __bfloat162float(wrow[256 + v]);
            const float w21o = __bfloat162float(wrow[288 + v]);
            const float w11e = __bfloat162float(wrow[320 + v]);
            const float wx1e = __bfloat162float(wrow[352 + v]);
            const float co0 = h1e1 * uz - h1e2 * uy;
            const float co1 = h1e2 * ux - h1e0 * uz;
            const float co2 = h1e0 * uy - h1e1 * ux;
            const float ce0 = h1o1 * uz - h1o2 * uy;
            const float ce1 = h1o2 * ux - h1o0 * uz;
            const float ce2 = h1o0 * uy - h1o1 * ux;
            float t0 = 0.f, t1 = 0.f, t2 = 0.f;
            #pragma unroll
            for (int c = 0; c < 16; c++) {
                const float wl = Wlv[c * 32 + v];
                t0 = fmaf(eci[c * 3 + 0], wl, t0);
                t1 = fmaf(eci[c * 3 + 1], wl, t1);
                t2 = fmaf(eci[c * 3 + 2], wl, t2);
            }
            const float svv = sv[v];
            atomicAdd(arow + S + 3 * v + 0, w11o * h1o0 + w01o * svv * ux + wx1o * co0 + w21o * t0);
            atomicAdd(arow + S + 3 * v + 1, w11o * h1o1 + w01o * svv * uy + wx1o * co1 + w21o * t1);
            atomicAdd(arow + S + 3 * v + 2, w11o * h1o2 + w01o * svv * uz + wx1o * co2 + w21o * t2);
            atomicAdd(arow + 160 + 3 * v + 0, w11e * h1e0 + wx1e * ce0);
            atomicAdd(arow + 160 + 3 * v + 1, w11e * h1e1 + wx1e * ce1);
            atomicAdd(arow + 160 + 3 * v + 2, w11e * h1e2 + wx1e * ce2);
        }

        // m2
        if (l < 16) {
            const int c = l;
            const float w22  = __bfloat162float(wrow[384 + c]);
            const float w112 = __bfloat162float(wrow[400 + c]);
            const float w02  = __bfloat162float(wrow[416 + c]);
            float tl0 = 0, tl1 = 0, tl2 = 0, tl3 = 0, tl4 = 0;
            #pragma unroll
            for (int v = 0; v < 32; v++) {
                const float wv = Wvl[v * 16 + c];
                tl0 = fmaf(t112[v * 5 + 0], wv, tl0);
                tl1 = fmaf(t112[v * 5 + 1], wv, tl1);
                tl2 = fmaf(t112[v * 5 + 2], wv, tl2);
                tl3 = fmaf(t112[v * 5 + 3], wv, tl3);
                tl4 = fmaf(t112[v * 5 + 4], wv, tl4);
            }
            const float slc = sl[c];
            atomicAdd(arow + 256 + 5 * c + 0, w22 * h2s0 + w112 * tl0 + w02 * slc * y2a[0]);
            atomicAdd(arow + 256 + 5 * c + 1, w22 * h2s1 + w112 * tl1 + w02 * slc * y2a[1]);
            atomicAdd(arow + 256 + 5 * c + 2, w22 * h2s2 + w112 * tl2 + w02 * slc * y2a[2]);
            atomicAdd(arow + 256 + 5 * c + 3, w22 * h2s3 + w112 * tl3 + w02 * slc * y2a[3]);
            atomicAdd(arow + 256 + 5 * c + 4, w22 * h2s4 + w112 * tl4 + w02 * slc * y2a[4]);
        }
    }
}

// One wave per node: projections + FiLM + LayerNorm + equivariant RMS norms.
__global__ __launch_bounds__(256) void node_kernel(
    const float* __restrict__ h, const float* __restrict__ t_emb,
    const float* __restrict__ agg,
    const float* __restrict__ P0, const float* __restrict__ P1o,
    const float* __restrict__ P1e, const float* __restrict__ P2,
    const float* __restrict__ filmW, const float* __restrict__ filmb,
    float* __restrict__ out)
{
    __shared__ float lds[4][336 + 64];
    const int wid = threadIdx.x >> 6;
    const int l = threadIdx.x & 63;
    const int n = blockIdx.x * 4 + wid;
    if (n >= N_NODES) return;
    float* ag = lds[wid];
    float* tv = ag + 336;
    const float* arow = agg + (size_t)n * D;
    const float* hrow = h + (size_t)n * D;
    for (int i = l; i < 336; i += 64) ag[i] = arow[i];
    tv[l] = t_emb[(size_t)n * TDIM + l];

    const int c2 = 128 + l;
    const int c3 = 192 + (l & 15);
    float f0 = filmb[l], f1 = filmb[64 + l], f2 = filmb[c2], f3 = filmb[c3];
    #pragma unroll 4
    for (int t = 0; t < 64; t++) {
        const float tt = tv[t];
        const float* fr = filmW + t * FILMD;
        f0 = fmaf(tt, fr[l], f0);
        f1 = fmaf(tt, fr[64 + l], f1);
        f2 = fmaf(tt, fr[c2], f2);
        f3 = fmaf(tt, fr[c3], f3);
    }

    {
        float a0 = 0.f;
        #pragma unroll 4
        for (int j = 0; j < 64; j++) a0 = fmaf(ag[j], P0[j * 64 + l], a0);
        a0 = silu_f(a0);
        const float hn0 = hrow[l] + a0;
        const float mu = wsum64(hn0) * (1.0f / 64.0f);
        const float d0 = hn0 - mu;
        const float var = wsum64(d0 * d0) * (1.0f / 64.0f);
        out[(size_t)n * D + l] = d0 * rsqrtf(var + 1e-6f) * (1.f + f0) + f1;
    }

    {
        const int v = l & 31;
        const bool iso = (l < 32);
        const float* Pm = iso ? P1o : P1e;
        const int base = iso ? 64 : 160;
        float a0 = 0.f, a1 = 0.f, a2 = 0.f;
        #pragma unroll 4
        for (int u = 0; u < 32; u++) {
            const float p = Pm[u * 32 + v];
            a0 = fmaf(ag[base + 3 * u + 0], p, a0);
            a1 = fmaf(ag[base + 3 * u + 1], p, a1);
            a2 = fmaf(ag[base + 3 * u + 2], p, a2);
        }
        const float x0 = hrow[base + 3 * v + 0] + a0;
        const float x1 = hrow[base + 3 * v + 1] + a1;
        const float x2 = hrow[base + 3 * v + 2] + a2;
        const float ssq = x0 * x0 + x1 * x1 + x2 * x2;
        const float s = wsum32(ssq);
        const float rinv = rsqrtf(s * (1.f / 32.f) + 1e-6f);
        const float sc = (1.f + f2) * rinv;
        out[(size_t)n * D + base + 3 * v + 0] = x0 * sc;
        out[(size_t)n * D + base + 3 * v + 1] = x1 * sc;
        out[(size_t)n * D + base + 3 * v + 2] = x2 * sc;
    }

    {
        const int c = l & 15;
        float xk[5];
        float ssq = 0.f;
        #pragma unroll
        for (int k = 0; k < 5; k++) {
            float a = 0.f;
            #pragma unroll
            for (int u = 0; u < 16; u++) a = fmaf(ag[256 + 5 * u + k], P2[u * 16 + c], a);
            const float x = hrow[256 + 5 * c + k] + a;
            xk[k] = x;
            ssq += x * x;
        }
        const float s = wsum16(ssq);
        const float rinv = rsqrtf(s * (1.f / 16.f) + 1e-6f);
        const float sc = (1.f + f3) * rinv;
        if (l < 16) {
            #pragma unroll
            for (int k = 0; k < 5; k++) out[(size_t)n * D + 256 + 5 * c + k] = xk[k] * sc;
        }
    }
}

extern "C" void kernel_launch(void* const* d_in, const int* in_sizes, int n_in,
                              void* d_out, int out_size, void* d_ws, size_t ws_size,
                              hipStream_t stream)
{
    const float* h        = (const float*)d_in[0];
    const float* coords   = (const float*)d_in[1];
    const int*   eidx     = (const int*)d_in[2];
    const int*   etype    = (const int*)d_in[3];
    const int*   ebt      = (const int*)d_in[4];
    const int*   econj    = (const int*)d_in[5];
    const int*   ering    = (const int*)d_in[6];
    const int*   est      = (const int*)d_in[7];
    const float* eref     = (const float*)d_in[8];
    const float* t_emb    = (const float*)d_in[9];
    const float* type_emb = (const float*)d_in[10];
    const float* bt_emb   = (const float*)d_in[11];
    const float* conj_emb = (const float*)d_in[12];
    const float* ring_emb = (const float*)d_in[13];
    const float* st_emb   = (const float*)d_in[14];
    const float* refW     = (const float*)d_in[15];
    const float* refb     = (const float*)d_in[16];
    const float* W1       = (const float*)d_in[17];
    const float* b1       = (const float*)d_in[18];
    const float* W2       = (const float*)d_in[19];
    const float* b2       = (const float*)d_in[20];
    const float* Wvs      = (const float*)d_in[21];
    const float* Wls      = (const float*)d_in[22];
    const float* Wsv      = (const float*)d_in[23];
    const float* Wlv      = (const float*)d_in[24];
    const float* Wvl      = (const float*)d_in[25];
    const float* Wsl      = (const float*)d_in[26];
    const float* P0       = (const float*)d_in[27];
    const float* P1o      = (const float*)d_in[28];
    const float* P1e      = (const float*)d_in[29];
    const float* P2       = (const float*)d_in[30];
    const float* filmW    = (const float*)d_in[31];
    const float* filmb    = (const float*)d_in[32];

    float* out = (float*)d_out;
    float* agg = (float*)d_ws;                             // 25000*336*4 = 33.6 MB
    __hip_bfloat16* Wb1t = (__hip_bfloat16*)(agg + (size_t)N_NODES * D);  // 128*256 bf16
    __hip_bfloat16* Wb2t = Wb1t + 128 * 256;                              // 432*128 bf16

    hipMemsetAsync(agg, 0, (size_t)N_NODES * D * sizeof(float), stream);
    convert_weights<<<(432 * 128 + 255) / 256, 256, 0, stream>>>(W1, W2, Wb1t, Wb2t);

    edge_kernel<<<N_EDGES / 64, 256, 0, stream>>>(
        h, coords, eidx, etype, ebt, econj, ering, est, eref, t_emb,
        type_emb, bt_emb, conj_emb, ring_emb, st_emb, refW, refb,
        Wb1t, b1, Wb2t, b2, Wvs, Wls, Wsv, Wlv, Wvl, Wsl, agg);

    node_kernel<<<(N_NODES + 3) / 4, 256, 0, stream>>>(
        h, t_emb, agg, P0, P1o, P1e, P2, filmW, filmb, out);
}